// Round 7
// baseline (1032.773 us; speedup 1.0000x reference)
//
#include <hip/hip_runtime.h>
#include <hip/hip_bf16.h>
#include <cstdint>
#include <cstddef>

#define DI __device__ __forceinline__

typedef __bf16 bf16_t;
typedef bf16_t bf16x8 __attribute__((ext_vector_type(8)));
typedef float f32x4 __attribute__((ext_vector_type(4)));

constexpr int Vn = 4, Bn = 2, Hn = 32, Wn = 64, Zn = 13, Cn = 256, HIDn = 1024;
constexpr int Ln = Hn * Wn * Zn;                 // 26624
constexpr int BWn = Bn * (Hn / 4) * (Wn / 4) * Zn; // 3328 windows (B_)
constexpr int PB = Bn * Ln;                      // 53248 rows per variable
constexpr int ROWS = Vn * PB;                    // 212992

// ---------- global -> LDS direct staging (16B per lane) ----------
DI void gload_lds16(const void* g, void* l) {
  __builtin_amdgcn_global_load_lds(
      (const __attribute__((address_space(1))) void*)g,
      (__attribute__((address_space(3))) void*)l, 16, 0, 0);
}

DI unsigned short f2bf_bits(float f) {
  __hip_bfloat16 h = __float2bfloat16(f);
  return *reinterpret_cast<unsigned short*>(&h);
}

DI float gelu_f(float x) {
  // sigmoid-form tanh-GELU with v_rcp_f32 (no IEEE divide)
  float u = x * x;
  float w = x * fmaf(0.044715f, u, 1.0f);
  float e = __expf(-1.5957691216057308f * w);
  return x * __builtin_amdgcn_rcpf(1.0f + e);
}

// ---------- tiled weight transpose: src [V][K][N] f32 -> dst [V][N][K] bf16 ----------
__global__ __launch_bounds__(256) void transpose_tile_kernel(
    const float* __restrict__ src, __hip_bfloat16* __restrict__ dst, int K, int N) {
  __shared__ float S[64][65];
  const int n0 = blockIdx.x * 64, k0 = blockIdx.y * 64, v = blockIdx.z;
  const int tc = threadIdx.x & 63, tr = threadIdx.x >> 6;  // tr 0..3
#pragma unroll
  for (int i = 0; i < 16; ++i) {
    int kk = tr + i * 4;
    S[kk][tc] = src[((size_t)v * K + k0 + kk) * N + n0 + tc];
  }
  __syncthreads();
#pragma unroll
  for (int i = 0; i < 16; ++i) {
    int nn = tr + i * 4;
    dst[((size_t)v * N + n0 + nn) * K + k0 + tc] = __float2bfloat16(S[tc][nn]);
  }
}

// ---------- LN1 fused with cyclic shift + window partition ----------
__global__ __launch_bounds__(256) void ln1_kernel(
    const float* __restrict__ x0, const float* __restrict__ x1,
    const float* __restrict__ x2i, const float* __restrict__ x3,
    const float* __restrict__ g_, const float* __restrict__ b_,
    __hip_bfloat16* __restrict__ xw) {
  int gw = blockIdx.x * 4 + (threadIdx.x >> 6);
  int lane = threadIdx.x & 63;
  int v = gw / PB;
  int rem = gw - v * PB;
  int bw = rem >> 4, nn = rem & 15;
  int zb = bw % 13;
  int t = bw / 13;
  int wb = t & 15, t2 = t >> 4;
  int hb = t2 & 7, b = t2 >> 3;
  int hs = (hb * 4 + (nn >> 2) + 30) & 31;   // (h - 2) mod 32
  int wsrc = (wb * 4 + (nn & 3) + 62) & 63;  // (w - 2) mod 64
  size_t l = (size_t)(hs * 64 + wsrc) * 13 + zb;
  const float* xv = (v == 0) ? x0 : (v == 1) ? x1 : (v == 2) ? x2i : x3;
  const float* xp = xv + ((size_t)b * Ln + l) * 256;
  float4 val = *(const float4*)(xp + lane * 4);
  float s = val.x + val.y + val.z + val.w;
  float sq = val.x * val.x + val.y * val.y + val.z * val.z + val.w * val.w;
#pragma unroll
  for (int o = 32; o; o >>= 1) {
    s += __shfl_xor(s, o);
    sq += __shfl_xor(sq, o);
  }
  float mean = s * (1.0f / 256.0f);
  float var = sq * (1.0f / 256.0f) - mean * mean;
  float rstd = rsqrtf(var + 1e-5f);
  const float* gg = g_ + v * 256 + lane * 4;
  const float* bb = b_ + v * 256 + lane * 4;
  ushort4 o4;
  o4.x = f2bf_bits((val.x - mean) * rstd * gg[0] + bb[0]);
  o4.y = f2bf_bits((val.y - mean) * rstd * gg[1] + bb[1]);
  o4.z = f2bf_bits((val.z - mean) * rstd * gg[2] + bb[2]);
  o4.w = f2bf_bits((val.w - mean) * rstd * gg[3] + bb[3]);
  *reinterpret_cast<ushort4*>(xw + (size_t)gw * 256 + lane * 4) = o4;
}

// ---------- LN2 (straight rows, x2 lives in d_out) ----------
__global__ __launch_bounds__(256) void ln2_kernel(
    const float* __restrict__ x2, const float* __restrict__ g_,
    const float* __restrict__ b_, __hip_bfloat16* __restrict__ xm) {
  int r = blockIdx.x * 4 + (threadIdx.x >> 6);
  int lane = threadIdx.x & 63;
  int v = r / PB;
  const float* xp = x2 + (size_t)r * 256;
  float4 val = *(const float4*)(xp + lane * 4);
  float s = val.x + val.y + val.z + val.w;
  float sq = val.x * val.x + val.y * val.y + val.z * val.z + val.w * val.w;
#pragma unroll
  for (int o = 32; o; o >>= 1) {
    s += __shfl_xor(s, o);
    sq += __shfl_xor(sq, o);
  }
  float mean = s * (1.0f / 256.0f);
  float var = sq * (1.0f / 256.0f) - mean * mean;
  float rstd = rsqrtf(var + 1e-5f);
  const float* gg = g_ + v * 256 + lane * 4;
  const float* bb = b_ + v * 256 + lane * 4;
  ushort4 o4;
  o4.x = f2bf_bits((val.x - mean) * rstd * gg[0] + bb[0]);
  o4.y = f2bf_bits((val.y - mean) * rstd * gg[1] + bb[1]);
  o4.z = f2bf_bits((val.z - mean) * rstd * gg[2] + bb[2]);
  o4.w = f2bf_bits((val.w - mean) * rstd * gg[3] + bb[3]);
  *reinterpret_cast<ushort4*>(xm + (size_t)r * 256 + lane * 4) = o4;
}

// ---------- windowed attention (verified) ----------
__global__ __launch_bounds__(256) void attn_kernel(
    const __hip_bfloat16* __restrict__ qkvp, __hip_bfloat16* __restrict__ ctx) {
  __shared__ float P[4][16][17];
  int b_ = blockIdx.x;
  int v = blockIdx.y;
  int wid = threadIdx.x >> 6, lane = threadIdx.x & 63;
  int lm = lane & 15, hi = lane >> 4;
  const bf16_t* base = (const bf16_t*)qkvp + (size_t)(v * BWn + b_) * 16 * 768;
  const float scale = 0.17677669529663687f;  // 32^-0.5
  f32x4 zero = {0.f, 0.f, 0.f, 0.f};
#pragma unroll
  for (int hh = 0; hh < 2; ++hh) {
    int h = wid + 4 * hh;
    bf16x8 qf = *(const bf16x8*)(base + (size_t)lm * 768 + h * 32 + hi * 8);
    bf16x8 kf = *(const bf16x8*)(base + (size_t)lm * 768 + 256 + h * 32 + hi * 8);
    f32x4 s = __builtin_amdgcn_mfma_f32_16x16x32_bf16(qf, kf, zero, 0, 0, 0);
    float p0[4];
#pragma unroll
    for (int q = 0; q < 4; ++q) {
      float val = s[q] * scale;
      float mx = val;
#pragma unroll
      for (int o = 8; o >= 1; o >>= 1) mx = fmaxf(mx, __shfl_xor(mx, o));
      float e = __expf(val - mx);
      float sum = e;
#pragma unroll
      for (int o = 8; o >= 1; o >>= 1) sum += __shfl_xor(sum, o);
      p0[q] = e * __builtin_amdgcn_rcpf(sum);
    }
#pragma unroll
    for (int q = 0; q < 4; ++q) P[wid][hi * 4 + q][lm] = p0[q];
    bf16x8 pa;
#pragma unroll
    for (int j = 0; j < 8; ++j) pa[j] = (bf16_t)0.f;
    if (hi < 2) {
#pragma unroll
      for (int j = 0; j < 8; ++j) pa[j] = (bf16_t)P[wid][lm][hi * 8 + j];
    }
#pragma unroll
    for (int dh = 0; dh < 2; ++dh) {
      bf16x8 vf;
#pragma unroll
      for (int j = 0; j < 8; ++j) vf[j] = (bf16_t)0.f;
      if (hi < 2) {
#pragma unroll
        for (int j = 0; j < 8; ++j)
          vf[j] = base[(size_t)(hi * 8 + j) * 768 + 512 + h * 32 + dh * 16 + lm];
      }
      f32x4 c = __builtin_amdgcn_mfma_f32_16x16x32_bf16(pa, vf, zero, 0, 0, 0);
#pragma unroll
      for (int q = 0; q < 4; ++q) {
        int n = hi * 4 + q;
        int d = dh * 16 + lm;
        int r = n * 4 + v;
        int vo = r >> 4, no = r & 15;
        ctx[((size_t)(vo * BWn + b_) * 16 + no) * 256 + h * 32 + d] = __float2bfloat16(c[q]);
      }
    }
  }
}

// ---------- GEMM v6: 256x256 tile, 8 waves (2x4), 512 threads, BK=32,
// double-buffered 64KB LDS (prefetch-next-then-compute; loads in flight across
// the whole compute phase; single drain+barrier per K-step), XCD-chunked mapping,
// 2-bit XOR source swizzle (64B rows), LDS-staged coalesced epilogue stores.
// Wave tile 128x64: acc[8][4] f32x4.
// EPI: 0 = qkv (bias, bf16), 1 = proj (bias + window-reverse + roll + shortcut -> f32 x2),
//      2 = fc1 (bias + GELU, bf16), 3 = fc2 (bias + x2 RMW -> f32 out)
template <int EPI, int K, int N>
__global__ __launch_bounds__(512, 2) void gemm6(
    const __hip_bfloat16* __restrict__ A, const __hip_bfloat16* __restrict__ WT,
    const float* __restrict__ bias, __hip_bfloat16* __restrict__ outb,
    float* __restrict__ outf, const float* __restrict__ xi0,
    const float* __restrict__ xi1, const float* __restrict__ xi2,
    const float* __restrict__ xi3) {
  constexpr int NT = K / 32;
  constexpr int NC = N / 256;
  const int v = blockIdx.z;
  // XCD-chunked mapping (208 panels/var, 208 % 8 == 0 -> bijective)
  const int x = blockIdx.x;
  const int xcd = x & 7;
  const int j = x >> 3;
  const int c = j % NC;
  const int rp = xcd + 8 * (j / NC);
  const int rowBase = rp * 256;
  const int colBase = c * 256;

  const bf16_t* Av = (const bf16_t*)A + ((size_t)v * PB + rowBase) * K;
  const bf16_t* Wv = (const bf16_t*)WT + ((size_t)v * N + colBase) * K;

  // LDS: A dbuf 2x16KB @0, B dbuf 2x16KB @32768. Epilogue aliases all 64KB.
  __shared__ __align__(16) uint8_t smem[65536];

  const int tid = threadIdx.x, wid = tid >> 6, lane = tid & 63;
  const int wr = wid >> 2, wc = wid & 3;  // 2x4 wave grid, wave tile 128x64
  const int lm = lane & 15, hi = lane >> 4;
  const int rS = lane >> 2;               // 0..15 row within 16-row staging group
  const int gS = (lane & 3) ^ (rS & 3);   // pre-swizzled source granule (16B units)

  f32x4 acc[8][4];
#pragma unroll
  for (int m = 0; m < 8; ++m)
#pragma unroll
    for (int n = 0; n < 4; ++n) acc[m][n] = f32x4{0.f, 0.f, 0.f, 0.f};

  auto stage = [&](int buf, int t) {
    bf16_t* Ad = (bf16_t*)(smem + buf * 16384);
    bf16_t* Bd = (bf16_t*)(smem + 32768 + buf * 16384);
    // A: 16 groups of 16 rows (2/wave); B same -> 4 gload_lds per thread.
#pragma unroll
    for (int g = 0; g < 2; ++g) {
      int r0 = (wid * 2 + g) * 16;
      gload_lds16(Av + (size_t)(r0 + rS) * K + t * 32 + gS * 8, Ad + r0 * 32);
    }
#pragma unroll
    for (int g = 0; g < 2; ++g) {
      int r0 = (wid * 2 + g) * 16;
      gload_lds16(Wv + (size_t)(r0 + rS) * K + t * 32 + gS * 8, Bd + r0 * 32);
    }
  };

  stage(0, 0);
  __syncthreads();  // drains vmcnt(0): tile 0 resident

  for (int t = 0; t < NT; ++t) {
    const int cur = t & 1;
    if (t + 1 < NT) stage(cur ^ 1, t + 1);  // issue BEFORE compute: flies under MFMA
    const bf16_t* Ab = (const bf16_t*)(smem + cur * 16384);
    const bf16_t* Bb = (const bf16_t*)(smem + 32768 + cur * 16384);
    bf16x8 bfv[4];
#pragma unroll
    for (int n = 0; n < 4; ++n)
      bfv[n] = *(const bf16x8*)&Bb[(wc * 64 + n * 16 + lm) * 32 + (hi ^ (lm & 3)) * 8];
#pragma unroll
    for (int m = 0; m < 8; ++m) {
      bf16x8 af = *(const bf16x8*)&Ab[(wr * 128 + m * 16 + lm) * 32 + (hi ^ (lm & 3)) * 8];
#pragma unroll
      for (int n = 0; n < 4; ++n)
        acc[m][n] = __builtin_amdgcn_mfma_f32_16x16x32_bf16(af, bfv[n], acc[m][n], 0, 0, 0);
    }
    __syncthreads();  // drains vmcnt+lgkm: next tile resident, this tile's reads done
  }

  // ---- epilogue: per-wave 8KB LDS region, coalesced 16B stores ----
  uint8_t* ep = smem + wid * 8192;
  const int pr = lane >> 3, pc = lane & 7;

  if constexpr (EPI == 0 || EPI == 2) {
    ushort(*E)[72] = (ushort(*)[72])ep;  // 32 x 72 x 2B = 4608B
    float bcol[4];
#pragma unroll
    for (int n = 0; n < 4; ++n) bcol[n] = bias[v * N + colBase + wc * 64 + n * 16 + lm];
#pragma unroll
    for (int ph = 0; ph < 4; ++ph) {
#pragma unroll
      for (int mm = 0; mm < 2; ++mm) {
        int m = ph * 2 + mm;
#pragma unroll
        for (int q = 0; q < 4; ++q) {
          int lr = mm * 16 + hi * 4 + q;
#pragma unroll
          for (int n = 0; n < 4; ++n) {
            float val = acc[m][n][q] + bcol[n];
            if constexpr (EPI == 2) val = gelu_f(val);
            E[lr][n * 16 + lm] = f2bf_bits(val);
          }
        }
      }
#pragma unroll
      for (int p = 0; p < 4; ++p) {
        int lr = p * 8 + pr;
        bf16x8 valv = *(const bf16x8*)&E[lr][pc * 8];
        size_t grow = (size_t)v * PB + rowBase + wr * 128 + ph * 32 + lr;
        int gcol = colBase + wc * 64 + pc * 8;
        *(bf16x8*)&outb[grow * N + gcol] = valv;
      }
    }
  } else {
    float(*F)[36] = (float(*)[36])ep;  // 32 x 36 x 4B = 4608B
#pragma unroll
    for (int ph = 0; ph < 4; ++ph) {
#pragma unroll
      for (int h2 = 0; h2 < 2; ++h2) {
#pragma unroll
        for (int mm = 0; mm < 2; ++mm) {
          int m = ph * 2 + mm;
#pragma unroll
          for (int q = 0; q < 4; ++q) {
            int lr = mm * 16 + hi * 4 + q;
#pragma unroll
            for (int n2 = 0; n2 < 2; ++n2) F[lr][n2 * 16 + lm] = acc[m][h2 * 2 + n2][q];
          }
        }
#pragma unroll
        for (int p = 0; p < 4; ++p) {
          int lr = p * 8 + pr;
          f32x4 a4 = *(const f32x4*)&F[lr][pc * 4];
          int rowv = rowBase + wr * 128 + ph * 32 + lr;
          int gcol = colBase + wc * 64 + h2 * 32 + pc * 4;
          f32x4 b4 = *(const f32x4*)&bias[v * N + gcol];
          if constexpr (EPI == 1) {
            int b_ = rowv >> 4, nn = rowv & 15;
            int zb = b_ % 13;
            int tt = b_ / 13;
            int wb = tt & 15, tt2 = tt >> 4;
            int hb = tt2 & 7, bb = tt2 >> 3;
            int h2v = (hb * 4 + (nn >> 2) + 2) & 31;  // window reverse + roll(+2)
            int w2v = (wb * 4 + (nn & 3) + 2) & 63;
            size_t l = (size_t)(h2v * 64 + w2v) * 13 + zb;
            const float* xv = (v == 0) ? xi0 : (v == 1) ? xi1 : (v == 2) ? xi2 : xi3;
            f32x4 x4 = *(const f32x4*)(xv + ((size_t)bb * Ln + l) * 256 + gcol);
            f32x4 o4 = a4 + b4 + x4;
            *(f32x4*)(outf + (((size_t)v * Bn + bb) * Ln + l) * 256 + gcol) = o4;
          } else {  // EPI == 3: RMW residual
            float* o = outf + ((size_t)v * PB + rowv) * 256 + gcol;
            f32x4 cur4 = *(const f32x4*)o;
            f32x4 o4 = cur4 + a4 + b4;
            *(f32x4*)o = o4;
          }
        }
      }
    }
  }
}

extern "C" void kernel_launch(void* const* d_in, const int* in_sizes, int n_in,
                              void* d_out, int out_size, void* d_ws, size_t ws_size,
                              hipStream_t stream) {
  const float* x0 = (const float*)d_in[0];
  const float* x1 = (const float*)d_in[1];
  const float* x2i = (const float*)d_in[2];
  const float* x3 = (const float*)d_in[3];
  const float* qkv_w = (const float*)d_in[4];
  const float* qkv_b = (const float*)d_in[5];
  const float* proj_w = (const float*)d_in[6];
  const float* proj_b = (const float*)d_in[7];
  const float* n1g = (const float*)d_in[8];
  const float* n1b = (const float*)d_in[9];
  const float* n2g = (const float*)d_in[10];
  const float* n2b = (const float*)d_in[11];
  const float* fc1_w = (const float*)d_in[12];
  const float* fc1_b = (const float*)d_in[13];
  const float* fc2_w = (const float*)d_in[14];
  const float* fc2_b = (const float*)d_in[15];
  float* out = (float*)d_out;  // doubles as x2 buffer

  uint8_t* ws = (uint8_t*)d_ws;
  size_t off = 0;
  auto alloc = [&](size_t bytes) -> void* {
    void* p = ws + off;
    off += (bytes + 255) & ~(size_t)255;
    return p;
  };
  __hip_bfloat16* wqkvT = (__hip_bfloat16*)alloc((size_t)Vn * Cn * 768 * 2);
  __hip_bfloat16* wprojT = (__hip_bfloat16*)alloc((size_t)Vn * Cn * Cn * 2);
  __hip_bfloat16* wfc1T = (__hip_bfloat16*)alloc((size_t)Vn * Cn * HIDn * 2);
  __hip_bfloat16* wfc2T = (__hip_bfloat16*)alloc((size_t)Vn * HIDn * Cn * 2);
  __hip_bfloat16* xw = (__hip_bfloat16*)alloc((size_t)ROWS * Cn * 2);     // xw / ctx / xm
  __hip_bfloat16* qkvb = (__hip_bfloat16*)alloc((size_t)ROWS * HIDn * 2); // qkv / h

  transpose_tile_kernel<<<dim3(768 / 64, 256 / 64, Vn), 256, 0, stream>>>(qkv_w, wqkvT, 256, 768);
  transpose_tile_kernel<<<dim3(256 / 64, 256 / 64, Vn), 256, 0, stream>>>(proj_w, wprojT, 256, 256);
  transpose_tile_kernel<<<dim3(1024 / 64, 256 / 64, Vn), 256, 0, stream>>>(fc1_w, wfc1T, 256, 1024);
  transpose_tile_kernel<<<dim3(256 / 64, 1024 / 64, Vn), 256, 0, stream>>>(fc2_w, wfc2T, 1024, 256);

  ln1_kernel<<<ROWS / 4, 256, 0, stream>>>(x0, x1, x2i, x3, n1g, n1b, xw);

  gemm6<0, 256, 768><<<dim3(208 * 3, 1, Vn), 512, 0, stream>>>(
      xw, wqkvT, qkv_b, qkvb, nullptr, nullptr, nullptr, nullptr, nullptr);

  attn_kernel<<<dim3(BWn, Vn), 256, 0, stream>>>(qkvb, xw /*ctx*/);

  gemm6<1, 256, 256><<<dim3(208, 1, Vn), 512, 0, stream>>>(
      xw /*ctx*/, wprojT, proj_b, nullptr, out /*x2*/, x0, x1, x2i, x3);

  ln2_kernel<<<ROWS / 4, 256, 0, stream>>>(out /*x2*/, n2g, n2b, xw /*xm*/);

  gemm6<2, 256, 1024><<<dim3(208 * 4, 1, Vn), 512, 0, stream>>>(
      xw /*xm*/, wfc1T, fc1_b, qkvb /*h*/, nullptr, nullptr, nullptr, nullptr, nullptr);

  gemm6<3, 1024, 256><<<dim3(208, 1, Vn), 512, 0, stream>>>(
      qkvb /*h*/, wfc2T, fc2_b, nullptr, out, nullptr, nullptr, nullptr, nullptr);
}

// Round 8
// 919.001 us; speedup vs baseline: 1.1238x; 1.1238x over previous
//
#include <hip/hip_runtime.h>
#include <hip/hip_bf16.h>
#include <cstdint>
#include <cstddef>

#define DI __device__ __forceinline__

typedef __bf16 bf16_t;
typedef bf16_t bf16x8 __attribute__((ext_vector_type(8)));
typedef float f32x4 __attribute__((ext_vector_type(4)));

constexpr int Vn = 4, Bn = 2, Hn = 32, Wn = 64, Zn = 13, Cn = 256, HIDn = 1024;
constexpr int Ln = Hn * Wn * Zn;                 // 26624
constexpr int BWn = Bn * (Hn / 4) * (Wn / 4) * Zn; // 3328 windows (B_)
constexpr int PB = Bn * Ln;                      // 53248 rows per variable
constexpr int ROWS = Vn * PB;                    // 212992

// ---------- global -> LDS direct staging (16B per lane; LDS dest wave-uniform) ----------
DI void gload_lds16(const void* g, void* l) {
  __builtin_amdgcn_global_load_lds(
      (const __attribute__((address_space(1))) void*)g,
      (__attribute__((address_space(3))) void*)l, 16, 0, 0);
}

DI unsigned short f2bf_bits(float f) {
  __hip_bfloat16 h = __float2bfloat16(f);
  return *reinterpret_cast<unsigned short*>(&h);
}

DI float gelu_f(float x) {
  // sigmoid-form tanh-GELU with v_rcp_f32 (no IEEE divide)
  float u = x * x;
  float w = x * fmaf(0.044715f, u, 1.0f);
  float e = __expf(-1.5957691216057308f * w);
  return x * __builtin_amdgcn_rcpf(1.0f + e);
}

// ---------- tiled weight transpose: src [V][K][N] f32 -> dst [V][N][K] bf16 ----------
__global__ __launch_bounds__(256) void transpose_tile_kernel(
    const float* __restrict__ src, __hip_bfloat16* __restrict__ dst, int K, int N) {
  __shared__ float S[64][65];
  const int n0 = blockIdx.x * 64, k0 = blockIdx.y * 64, v = blockIdx.z;
  const int tc = threadIdx.x & 63, tr = threadIdx.x >> 6;  // tr 0..3
#pragma unroll
  for (int i = 0; i < 16; ++i) {
    int kk = tr + i * 4;
    S[kk][tc] = src[((size_t)v * K + k0 + kk) * N + n0 + tc];
  }
  __syncthreads();
#pragma unroll
  for (int i = 0; i < 16; ++i) {
    int nn = tr + i * 4;
    dst[((size_t)v * N + n0 + nn) * K + k0 + tc] = __float2bfloat16(S[tc][nn]);
  }
}

// ---------- LN1 fused with cyclic shift + window partition ----------
__global__ __launch_bounds__(256) void ln1_kernel(
    const float* __restrict__ x0, const float* __restrict__ x1,
    const float* __restrict__ x2i, const float* __restrict__ x3,
    const float* __restrict__ g_, const float* __restrict__ b_,
    __hip_bfloat16* __restrict__ xw) {
  int gw = blockIdx.x * 4 + (threadIdx.x >> 6);
  int lane = threadIdx.x & 63;
  int v = gw / PB;
  int rem = gw - v * PB;
  int bw = rem >> 4, nn = rem & 15;
  int zb = bw % 13;
  int t = bw / 13;
  int wb = t & 15, t2 = t >> 4;
  int hb = t2 & 7, b = t2 >> 3;
  int hs = (hb * 4 + (nn >> 2) + 30) & 31;   // (h - 2) mod 32
  int wsrc = (wb * 4 + (nn & 3) + 62) & 63;  // (w - 2) mod 64
  size_t l = (size_t)(hs * 64 + wsrc) * 13 + zb;
  const float* xv = (v == 0) ? x0 : (v == 1) ? x1 : (v == 2) ? x2i : x3;
  const float* xp = xv + ((size_t)b * Ln + l) * 256;
  float4 val = *(const float4*)(xp + lane * 4);
  float s = val.x + val.y + val.z + val.w;
  float sq = val.x * val.x + val.y * val.y + val.z * val.z + val.w * val.w;
#pragma unroll
  for (int o = 32; o; o >>= 1) {
    s += __shfl_xor(s, o);
    sq += __shfl_xor(sq, o);
  }
  float mean = s * (1.0f / 256.0f);
  float var = sq * (1.0f / 256.0f) - mean * mean;
  float rstd = rsqrtf(var + 1e-5f);
  const float* gg = g_ + v * 256 + lane * 4;
  const float* bb = b_ + v * 256 + lane * 4;
  ushort4 o4;
  o4.x = f2bf_bits((val.x - mean) * rstd * gg[0] + bb[0]);
  o4.y = f2bf_bits((val.y - mean) * rstd * gg[1] + bb[1]);
  o4.z = f2bf_bits((val.z - mean) * rstd * gg[2] + bb[2]);
  o4.w = f2bf_bits((val.w - mean) * rstd * gg[3] + bb[3]);
  *reinterpret_cast<ushort4*>(xw + (size_t)gw * 256 + lane * 4) = o4;
}

// ---------- windowed attention (verified) ----------
__global__ __launch_bounds__(256) void attn_kernel(
    const __hip_bfloat16* __restrict__ qkvp, __hip_bfloat16* __restrict__ ctx) {
  __shared__ float P[4][16][17];
  int b_ = blockIdx.x;
  int v = blockIdx.y;
  int wid = threadIdx.x >> 6, lane = threadIdx.x & 63;
  int lm = lane & 15, hi = lane >> 4;
  const bf16_t* base = (const bf16_t*)qkvp + (size_t)(v * BWn + b_) * 16 * 768;
  const float scale = 0.17677669529663687f;  // 32^-0.5
  f32x4 zero = {0.f, 0.f, 0.f, 0.f};
#pragma unroll
  for (int hh = 0; hh < 2; ++hh) {
    int h = wid + 4 * hh;
    bf16x8 qf = *(const bf16x8*)(base + (size_t)lm * 768 + h * 32 + hi * 8);
    bf16x8 kf = *(const bf16x8*)(base + (size_t)lm * 768 + 256 + h * 32 + hi * 8);
    f32x4 s = __builtin_amdgcn_mfma_f32_16x16x32_bf16(qf, kf, zero, 0, 0, 0);
    float p0[4];
#pragma unroll
    for (int q = 0; q < 4; ++q) {
      float val = s[q] * scale;
      float mx = val;
#pragma unroll
      for (int o = 8; o >= 1; o >>= 1) mx = fmaxf(mx, __shfl_xor(mx, o));
      float e = __expf(val - mx);
      float sum = e;
#pragma unroll
      for (int o = 8; o >= 1; o >>= 1) sum += __shfl_xor(sum, o);
      p0[q] = e * __builtin_amdgcn_rcpf(sum);
    }
#pragma unroll
    for (int q = 0; q < 4; ++q) P[wid][hi * 4 + q][lm] = p0[q];
    bf16x8 pa;
#pragma unroll
    for (int j = 0; j < 8; ++j) pa[j] = (bf16_t)0.f;
    if (hi < 2) {
#pragma unroll
      for (int j = 0; j < 8; ++j) pa[j] = (bf16_t)P[wid][lm][hi * 8 + j];
    }
#pragma unroll
    for (int dh = 0; dh < 2; ++dh) {
      bf16x8 vf;
#pragma unroll
      for (int j = 0; j < 8; ++j) vf[j] = (bf16_t)0.f;
      if (hi < 2) {
#pragma unroll
        for (int j = 0; j < 8; ++j)
          vf[j] = base[(size_t)(hi * 8 + j) * 768 + 512 + h * 32 + dh * 16 + lm];
      }
      f32x4 c = __builtin_amdgcn_mfma_f32_16x16x32_bf16(pa, vf, zero, 0, 0, 0);
#pragma unroll
      for (int q = 0; q < 4; ++q) {
        int n = hi * 4 + q;
        int d = dh * 16 + lm;
        int r = n * 4 + v;
        int vo = r >> 4, no = r & 15;
        ctx[((size_t)(vo * BWn + b_) * 16 + no) * 256 + h * 32 + d] = __float2bfloat16(c[q]);
      }
    }
  }
}

// ---------- GEMM v4 (verified r5 structure): 128x128 tile, 4 waves, BK=64,
// single-buffered 32KB + epilogue staging (40KB -> 3 blocks/CU), XCD-chunked mapping.
// EPI: 0 = qkv (bias, bf16), 1 = proj (bias + window-reverse + roll + shortcut -> f32 x2)
template <int EPI, int K, int N>
__global__ __launch_bounds__(256, 3) void gemm4(
    const __hip_bfloat16* __restrict__ A, const __hip_bfloat16* __restrict__ WT,
    const float* __restrict__ bias, __hip_bfloat16* __restrict__ outb,
    float* __restrict__ outf, const float* __restrict__ xi0,
    const float* __restrict__ xi1, const float* __restrict__ xi2,
    const float* __restrict__ xi3) {
  constexpr int NT = K / 64;
  constexpr int NC = N / 128;
  const int v = blockIdx.z;
  const int x = blockIdx.x;
  const int xcd = x & 7;
  const int j = x >> 3;
  const int c = j % NC;
  const int r = xcd + 8 * (j / NC);
  const int rowBase = r * 128;
  const int colBase = c * 128;

  const bf16_t* Av = (const bf16_t*)A + ((size_t)v * PB + rowBase) * K;
  const bf16_t* Wv = (const bf16_t*)WT + ((size_t)v * N + colBase) * K;

  __shared__ __align__(16) uint8_t smem[40960];
  bf16_t(*As)[64] = (bf16_t(*)[64])smem;             // [128][64]
  bf16_t(*Bs)[64] = (bf16_t(*)[64])(smem + 16384);   // [128][64]

  const int tid = threadIdx.x, wid = tid >> 6, lane = tid & 63;
  const int wr = wid >> 1, wc = wid & 1;
  const int lm = lane & 15, hi = lane >> 4;
  const int rA = lane >> 3;
  const int lg = (lane & 7) ^ rA;

  f32x4 acc[4][4];
#pragma unroll
  for (int m = 0; m < 4; ++m)
#pragma unroll
    for (int n = 0; n < 4; ++n) acc[m][n] = f32x4{0.f, 0.f, 0.f, 0.f};

  for (int t = 0; t < NT; ++t) {
    if (t) __syncthreads();
#pragma unroll
    for (int g = 0; g < 4; ++g) {
      int grp = wid * 4 + g;
      gload_lds16(Av + (size_t)(grp * 8 + rA) * K + t * 64 + lg * 8, &As[grp * 8][0]);
    }
#pragma unroll
    for (int g = 0; g < 4; ++g) {
      int grp = wid * 4 + g;
      gload_lds16(Wv + (size_t)(grp * 8 + rA) * K + t * 64 + lg * 8, &Bs[grp * 8][0]);
    }
    __syncthreads();
#pragma unroll
    for (int kk = 0; kk < 2; ++kk) {
      bf16x8 af[4], bfv[4];
#pragma unroll
      for (int m = 0; m < 4; ++m) {
        const int rr = wr * 64 + m * 16 + lm;
        af[m] = *(const bf16x8*)&As[rr][((kk * 4 + hi) ^ (lm & 7)) * 8];
      }
#pragma unroll
      for (int n = 0; n < 4; ++n) {
        const int rr = wc * 64 + n * 16 + lm;
        bfv[n] = *(const bf16x8*)&Bs[rr][((kk * 4 + hi) ^ (lm & 7)) * 8];
      }
#pragma unroll
      for (int m = 0; m < 4; ++m)
#pragma unroll
        for (int n = 0; n < 4; ++n)
          acc[m][n] = __builtin_amdgcn_mfma_f32_16x16x32_bf16(af[m], bfv[n], acc[m][n], 0, 0, 0);
    }
  }

  __syncthreads();
  uint8_t* ep = smem + wid * 10240;

  if constexpr (EPI == 0) {
    ushort(*E)[72] = (ushort(*)[72])ep;
    float bcol[4];
#pragma unroll
    for (int n = 0; n < 4; ++n) bcol[n] = bias[v * N + colBase + wc * 64 + n * 16 + lm];
#pragma unroll
    for (int m = 0; m < 4; ++m)
#pragma unroll
      for (int q = 0; q < 4; ++q) {
        int lr = m * 16 + hi * 4 + q;
#pragma unroll
        for (int n = 0; n < 4; ++n) E[lr][n * 16 + lm] = f2bf_bits(acc[m][n][q] + bcol[n]);
      }
    const int pr = lane >> 3, pc = lane & 7;
#pragma unroll
    for (int p = 0; p < 8; ++p) {
      int lr = p * 8 + pr;
      bf16x8 val = *(const bf16x8*)&E[lr][pc * 8];
      size_t grow = (size_t)v * PB + rowBase + wr * 64 + lr;
      int gcol = colBase + wc * 64 + pc * 8;
      *(bf16x8*)&outb[grow * N + gcol] = val;
    }
  } else {
    float(*F)[36] = (float(*)[36])ep;
    const int pr = lane >> 3, pc = lane & 7;
#pragma unroll
    for (int h2 = 0; h2 < 2; ++h2) {
#pragma unroll
      for (int m = 0; m < 4; ++m)
#pragma unroll
        for (int q = 0; q < 4; ++q) {
          int lr = m * 16 + hi * 4 + q;
#pragma unroll
          for (int n2 = 0; n2 < 2; ++n2) F[lr][n2 * 16 + lm] = acc[m][h2 * 2 + n2][q];
        }
#pragma unroll
      for (int p = 0; p < 8; ++p) {
        int lr = p * 8 + pr;
        f32x4 a4 = *(const f32x4*)&F[lr][pc * 4];
        int rowv = rowBase + wr * 64 + lr;
        int gcol = colBase + wc * 64 + h2 * 32 + pc * 4;
        f32x4 b4 = *(const f32x4*)&bias[v * N + gcol];
        int b_ = rowv >> 4, nn = rowv & 15;
        int zb = b_ % 13;
        int tt = b_ / 13;
        int wb = tt & 15, tt2 = tt >> 4;
        int hb = tt2 & 7, bb = tt2 >> 3;
        int h2v = (hb * 4 + (nn >> 2) + 2) & 31;
        int w2v = (wb * 4 + (nn & 3) + 2) & 63;
        size_t l = (size_t)(h2v * 64 + w2v) * 13 + zb;
        const float* xv = (v == 0) ? xi0 : (v == 1) ? xi1 : (v == 2) ? xi2 : xi3;
        f32x4 x4 = *(const f32x4*)(xv + ((size_t)bb * Ln + l) * 256 + gcol);
        f32x4 o4 = a4 + b4 + x4;
        *(f32x4*)(outf + (((size_t)v * Bn + bb) * Ln + l) * 256 + gcol) = o4;
      }
      if (h2 == 0) __builtin_amdgcn_s_waitcnt(0);
    }
  }
}

// ---------- fused MLP: LN2 + fc1 + GELU + fc2 + residual, one 128-row panel/block ----------
// 512 threads, 8 waves. LDS 128KB: regA 64KB (xn then W1 chunk), regH 32KB (h), regC 32KB (W2 k-halfchunk).
// All LDS tiles XOR-swizzled pg = g ^ (row&7) on 16B granules (<=2 lanes/bank = free).
// acc2 (fc2 out, 64 VGPR) persists across 8 HID chunks; h never touches HBM.
__global__ __launch_bounds__(512, 1) void mlp_fused(
    const float* __restrict__ x2,            // d_out rows (read: LN + residual)
    const __hip_bfloat16* __restrict__ W1T,  // [V][1024][256]
    const __hip_bfloat16* __restrict__ W2T,  // [V][256][1024]
    const float* __restrict__ b1, const float* __restrict__ b2,
    const float* __restrict__ g2, const float* __restrict__ bt2,
    float* __restrict__ outp) {
  const int v = blockIdx.z;
  const size_t gRow0 = (size_t)v * PB + (size_t)blockIdx.x * 128;

  __shared__ __align__(16) uint8_t smem[131072];
  uint8_t* regA = smem;            // 64KB: xn [128][512B] -> W1 chunk [128][512B]
  uint8_t* regH = smem + 65536;    // 32KB: h [128][256B]
  uint8_t* regC = smem + 98304;    // 32KB: W2 [256 cols][64 k]

  const int tid = threadIdx.x, wid = tid >> 6, lane = tid & 63;
  const int lm = lane & 15, hi = lane >> 4;
  const int wr = wid >> 1;  // 0..3: rows wr*32
  const int wc = wid & 1;   // 0..1: GEMM1 cols wc*64 / GEMM2 cols wc*128

  // ---- Phase 0: LN2, 16 rows per wave, write bf16 xn into regA (swizzled) ----
  const float* gg = g2 + v * 256;
  const float* gb = bt2 + v * 256;
  {
    float g4[4], b4l[4];
#pragma unroll
    for (int e = 0; e < 4; ++e) { g4[e] = gg[lane * 4 + e]; b4l[e] = gb[lane * 4 + e]; }
    for (int i = 0; i < 16; ++i) {
      int row = wid * 16 + i;
      const float* xp = x2 + (gRow0 + row) * 256;
      float4 val = *(const float4*)(xp + lane * 4);
      float s = val.x + val.y + val.z + val.w;
      float sq = val.x * val.x + val.y * val.y + val.z * val.z + val.w * val.w;
#pragma unroll
      for (int o = 32; o; o >>= 1) {
        s += __shfl_xor(s, o);
        sq += __shfl_xor(sq, o);
      }
      float mean = s * (1.0f / 256.0f);
      float var = sq * (1.0f / 256.0f) - mean * mean;
      float rstd = rsqrtf(var + 1e-5f);
      ushort4 o4;
      o4.x = f2bf_bits((val.x - mean) * rstd * g4[0] + b4l[0]);
      o4.y = f2bf_bits((val.y - mean) * rstd * g4[1] + b4l[1]);
      o4.z = f2bf_bits((val.z - mean) * rstd * g4[2] + b4l[2]);
      o4.w = f2bf_bits((val.w - mean) * rstd * g4[3] + b4l[3]);
      int pg = (lane >> 1) ^ (row & 7);
      *(ushort4*)(regA + row * 512 + pg * 16 + (lane & 1) * 8) = o4;
    }
  }
  __syncthreads();

  // ---- Phase 1: hoist this wave's A-fragments (rows wr*32..+32, all K) to registers ----
  bf16x8 afx[2][4][2];
#pragma unroll
  for (int mm = 0; mm < 2; ++mm)
#pragma unroll
    for (int t = 0; t < 4; ++t)
#pragma unroll
      for (int kk = 0; kk < 2; ++kk) {
        int row = wr * 32 + mm * 16 + lm;
        int g = t * 8 + kk * 4 + hi;
        int pg = g ^ (row & 7);
        afx[mm][t][kk] = *(const bf16x8*)(regA + row * 512 + pg * 16);
      }
  __syncthreads();  // all af reads done before W1 staging overwrites regA

  f32x4 acc2[2][8];
#pragma unroll
  for (int mm = 0; mm < 2; ++mm)
#pragma unroll
    for (int nn = 0; nn < 8; ++nn) acc2[mm][nn] = f32x4{0.f, 0.f, 0.f, 0.f};

  const bf16_t* W1v = (const bf16_t*)W1T + (size_t)v * 1024 * 256;
  const bf16_t* W2v = (const bf16_t*)W2T + (size_t)v * 256 * 1024;

  for (int hc = 0; hc < 8; ++hc) {
    // stage W1 chunk [128 n][256 k] into regA (4096 slots, 8 rounds) and
    // W2 k-half [256 cols][64 k] into regC (2048 slots, 4 rounds), pre-swizzled source
#pragma unroll
    for (int rd = 0; rd < 8; ++rd) {
      int s = (rd * 8 + wid) * 64 + lane;
      int row = s >> 5, pg = s & 31;
      int g = pg ^ (row & 7);
      gload_lds16(W1v + (size_t)(hc * 128 + row) * 256 + g * 8, regA + (rd * 8 + wid) * 1024);
    }
#pragma unroll
    for (int rd = 0; rd < 4; ++rd) {
      int s = (rd * 8 + wid) * 64 + lane;
      int col = s >> 3, pg = s & 7;
      int g = pg ^ (col & 7);
      gload_lds16(W2v + (size_t)col * 1024 + hc * 128 + g * 8, regC + (rd * 8 + wid) * 1024);
    }
    __syncthreads();  // W1 + W2(t2=0) resident

    // ---- GEMM1: h_chunk(128x128) = xn(128x256) * W1chunk^T ----
    f32x4 acc1[2][4];
#pragma unroll
    for (int mm = 0; mm < 2; ++mm)
#pragma unroll
      for (int nn = 0; nn < 4; ++nn) acc1[mm][nn] = f32x4{0.f, 0.f, 0.f, 0.f};
#pragma unroll
    for (int t = 0; t < 4; ++t)
#pragma unroll
      for (int kk = 0; kk < 2; ++kk) {
        bf16x8 wf[4];
#pragma unroll
        for (int nn = 0; nn < 4; ++nn) {
          int row = wc * 64 + nn * 16 + lm;
          int g = t * 8 + kk * 4 + hi;
          int pg = g ^ (row & 7);
          wf[nn] = *(const bf16x8*)(regA + row * 512 + pg * 16);
        }
#pragma unroll
        for (int mm = 0; mm < 2; ++mm)
#pragma unroll
          for (int nn = 0; nn < 4; ++nn)
            acc1[mm][nn] =
                __builtin_amdgcn_mfma_f32_16x16x32_bf16(afx[mm][t][kk], wf[nn], acc1[mm][nn], 0, 0, 0);
      }

    // ---- bias + GELU -> h (bf16, swizzled) ----
    float b1c[4];
#pragma unroll
    for (int nn = 0; nn < 4; ++nn) b1c[nn] = b1[v * 1024 + hc * 128 + wc * 64 + nn * 16 + lm];
#pragma unroll
    for (int mm = 0; mm < 2; ++mm)
#pragma unroll
      for (int nn = 0; nn < 4; ++nn)
#pragma unroll
        for (int q = 0; q < 4; ++q) {
          int row = wr * 32 + mm * 16 + hi * 4 + q;
          int col = wc * 64 + nn * 16 + lm;
          float val = gelu_f(acc1[mm][nn][q] + b1c[nn]);
          int pg = (col >> 3) ^ (row & 7);
          *(ushort*)(regH + row * 256 + pg * 16 + (col & 7) * 2) = f2bf_bits(val);
        }
    __syncthreads();  // h visible to all waves

    // ---- GEMM2 over the two 64-k halves of this chunk ----
#pragma unroll
    for (int t2 = 0; t2 < 2; ++t2) {
      if (t2 == 1) {
        __syncthreads();  // regC(t2=0) reads done
#pragma unroll
        for (int rd = 0; rd < 4; ++rd) {
          int s = (rd * 8 + wid) * 64 + lane;
          int col = s >> 3, pg = s & 7;
          int g = pg ^ (col & 7);
          gload_lds16(W2v + (size_t)col * 1024 + hc * 128 + 64 + g * 8, regC + (rd * 8 + wid) * 1024);
        }
        __syncthreads();  // regC(t2=1) resident
      }
#pragma unroll
      for (int kk = 0; kk < 2; ++kk) {
        bf16x8 hf[2];
#pragma unroll
        for (int mm = 0; mm < 2; ++mm) {
          int row = wr * 32 + mm * 16 + lm;
          int g = t2 * 8 + kk * 4 + hi;     // h granule within 16
          int pg = g ^ (row & 7);
          hf[mm] = *(const bf16x8*)(regH + row * 256 + pg * 16);
        }
#pragma unroll
        for (int nn = 0; nn < 8; ++nn) {
          int col = wc * 128 + nn * 16 + lm;
          int g = kk * 4 + hi;              // W2 half-chunk granule within 8
          int pg = g ^ (col & 7);
          bf16x8 w2f = *(const bf16x8*)(regC + col * 128 + pg * 16);
#pragma unroll
          for (int mm = 0; mm < 2; ++mm)
            acc2[mm][nn] = __builtin_amdgcn_mfma_f32_16x16x32_bf16(hf[mm], w2f, acc2[mm][nn], 0, 0, 0);
        }
      }
    }
    __syncthreads();  // regC + regH reads done before next chunk's stages/writes
  }

  // ---- epilogue: bias + x2 residual RMW, LDS-staged coalesced f32x4 ----
  float(*F)[36] = (float(*)[36])(smem + wid * 8192);  // per-wave 4608B in freed regA
  const int pr = lane >> 3, pc = lane & 7;
#pragma unroll
  for (int ps = 0; ps < 4; ++ps) {
#pragma unroll
    for (int mm = 0; mm < 2; ++mm)
#pragma unroll
      for (int q = 0; q < 4; ++q) {
        int lr = mm * 16 + hi * 4 + q;
#pragma unroll
        for (int n2 = 0; n2 < 2; ++n2) F[lr][n2 * 16 + lm] = acc2[mm][ps * 2 + n2][q];
      }
#pragma unroll
    for (int p = 0; p < 4; ++p) {
      int lr = p * 8 + pr;
      f32x4 a4 = *(const f32x4*)&F[lr][pc * 4];
      size_t grow = gRow0 + wr * 32 + lr;
      int gcol = wc * 128 + ps * 32 + pc * 4;
      f32x4 b4 = *(const f32x4*)&b2[v * 256 + gcol];
      float* o = outp + grow * 256 + gcol;
      f32x4 cur = *(const f32x4*)o;
      *(f32x4*)o = cur + a4 + b4;
    }
    __builtin_amdgcn_s_waitcnt(0);  // drain lgkm before next pass overwrites F
  }
}

extern "C" void kernel_launch(void* const* d_in, const int* in_sizes, int n_in,
                              void* d_out, int out_size, void* d_ws, size_t ws_size,
                              hipStream_t stream) {
  const float* x0 = (const float*)d_in[0];
  const float* x1 = (const float*)d_in[1];
  const float* x2i = (const float*)d_in[2];
  const float* x3 = (const float*)d_in[3];
  const float* qkv_w = (const float*)d_in[4];
  const float* qkv_b = (const float*)d_in[5];
  const float* proj_w = (const float*)d_in[6];
  const float* proj_b = (const float*)d_in[7];
  const float* n1g = (const float*)d_in[8];
  const float* n1b = (const float*)d_in[9];
  const float* n2g = (const float*)d_in[10];
  const float* n2b = (const float*)d_in[11];
  const float* fc1_w = (const float*)d_in[12];
  const float* fc1_b = (const float*)d_in[13];
  const float* fc2_w = (const float*)d_in[14];
  const float* fc2_b = (const float*)d_in[15];
  float* out = (float*)d_out;  // doubles as x2 buffer

  uint8_t* ws = (uint8_t*)d_ws;
  size_t off = 0;
  auto alloc = [&](size_t bytes) -> void* {
    void* p = ws + off;
    off += (bytes + 255) & ~(size_t)255;
    return p;
  };
  __hip_bfloat16* wqkvT = (__hip_bfloat16*)alloc((size_t)Vn * Cn * 768 * 2);
  __hip_bfloat16* wprojT = (__hip_bfloat16*)alloc((size_t)Vn * Cn * Cn * 2);
  __hip_bfloat16* wfc1T = (__hip_bfloat16*)alloc((size_t)Vn * Cn * HIDn * 2);
  __hip_bfloat16* wfc2T = (__hip_bfloat16*)alloc((size_t)Vn * HIDn * Cn * 2);
  __hip_bfloat16* xw = (__hip_bfloat16*)alloc((size_t)ROWS * Cn * 2);     // xw / ctx
  __hip_bfloat16* qkvb = (__hip_bfloat16*)alloc((size_t)ROWS * 768 * 2);  // qkv

  transpose_tile_kernel<<<dim3(768 / 64, 256 / 64, Vn), 256, 0, stream>>>(qkv_w, wqkvT, 256, 768);
  transpose_tile_kernel<<<dim3(256 / 64, 256 / 64, Vn), 256, 0, stream>>>(proj_w, wprojT, 256, 256);
  transpose_tile_kernel<<<dim3(1024 / 64, 256 / 64, Vn), 256, 0, stream>>>(fc1_w, wfc1T, 256, 1024);
  transpose_tile_kernel<<<dim3(256 / 64, 1024 / 64, Vn), 256, 0, stream>>>(fc2_w, wfc2T, 1024, 256);

  ln1_kernel<<<ROWS / 4, 256, 0, stream>>>(x0, x1, x2i, x3, n1g, n1b, xw);

  gemm4<0, 256, 768><<<dim3(416 * 6, 1, Vn), 256, 0, stream>>>(
      xw, wqkvT, qkv_b, qkvb, nullptr, nullptr, nullptr, nullptr, nullptr);

  attn_kernel<<<dim3(BWn, Vn), 256, 0, stream>>>(qkvb, xw /*ctx*/);

  gemm4<1, 256, 256><<<dim3(416 * 2, 1, Vn), 256, 0, stream>>>(
      xw /*ctx*/, wprojT, proj_b, nullptr, out /*x2*/, x0, x1, x2i, x3);

  mlp_fused<<<dim3(416, 1, Vn), 512, 0, stream>>>(
      out /*x2*/, wfc1T, wfc2T, fc1_b, fc2_b, n2g, n2b, out);
}